// Round 13
// baseline (247.129 us; speedup 1.0000x reference)
//
#include <hip/hip_runtime.h>
#include <stdint.h>

#define N_NODES 1024
#define NCLS 10
#define KDIM 131072  // 1024*128

typedef unsigned short u16;
typedef _Float16 half8 __attribute__((ext_vector_type(8)));
typedef _Float16 h16x2 __attribute__((ext_vector_type(2)));
typedef __fp16 fp16x2 __attribute__((ext_vector_type(2)));
typedef float f32x4 __attribute__((ext_vector_type(4)));

__device__ __forceinline__ u16 f2h(float f) {
  union { _Float16 h; u16 u; } v; v.h = (_Float16)f; return v.u;
}
__device__ __forceinline__ uint32_t pkh(float a, float b) {
#if __has_builtin(__builtin_amdgcn_cvt_pkrtz)
  fp16x2 r = __builtin_amdgcn_cvt_pkrtz(a, b);
  union { fp16x2 v; uint32_t u; } c; c.v = r; return c.u;
#else
  union { _Float16 h[2]; uint32_t u; } c;
  c.h[0] = (_Float16)a; c.h[1] = (_Float16)b; return c.u;
#endif
}
__device__ __forceinline__ h16x2 u2h2(uint32_t u) {
  union { uint32_t u; h16x2 v; } c; c.u = u; return c.v;
}
__device__ __forceinline__ uint32_t h22u(h16x2 v) {
  union { h16x2 v; uint32_t u; } c; c.v = v; return c.u;
}

__device__ __forceinline__ void async_copy16(const u16* g, u16* l) {
  __builtin_amdgcn_global_load_lds(
      (const __attribute__((address_space(1))) void*)g,
      (__attribute__((address_space(3))) void*)l, 16, 0, 0);
}

// ---------------- single merged prep kernel ----------------
// W2/W3 are now stored in the per-lane MFMA B-fragment layout (like Wcf):
//   W2f flat idx (16 bits): [kq:2][kh:1][wn:1][nt:3][l:6][i8:3]
//     value = W2[row=wn*128+nt*16+(l&15)][k=kq*64+kh*32+((l>>4)<<3)+i8]
//   W3f flat idx (15 bits): [kq:2][kh:1][wn:1][nt:2][l:6][i8:3]
//     value = W3[row=wn*64+nt*16+(l&15)][k=kq*64+kh*32+((l>>4)<<3)+i8]
// so each lane's B fragment is ONE coalesced 16 B load from L2 — no Bs LDS.
// blockIdx ranges:
//   [0, 8192)        : Wcf
//   [8192, 8448)     : W2f (65536 elems)
//   [8448, 8576)     : W3f (32768 elems)
//   [8576, 8580)     : adj -> stencil tables (nbi, nbc, r)
//   [8580]           : w1p
//   [8581, 8591)     : out init
#define PREP_GRID 8591
__global__ __launch_bounds__(256) void prep_all_kernel(
    const float* __restrict__ W2, const float* __restrict__ W3,
    const float* __restrict__ Wc, const float* __restrict__ W1,
    const float* __restrict__ b1, const float* __restrict__ bc,
    const float* __restrict__ adj,
    u16* __restrict__ W2f, u16* __restrict__ W3f, u16* __restrict__ Wcf,
    float* __restrict__ w1p, int* __restrict__ nbi, float* __restrict__ nbc,
    float* __restrict__ r, float* __restrict__ out)
{
  int blk = blockIdx.x;
  int tid = threadIdx.x;
  if (blk < 8192) {                       // Wcf: i over KDIM*16, coalesced store
    int i = blk * 256 + tid;
    int kb  = i >> 9;
    int l   = (i >> 3) & 63;
    int i8  = i & 7;
    int cls = l & 15;
    int kpos = kb * 32 + ((l >> 4) << 3) + i8;
    Wcf[i] = (cls < NCLS) ? f2h(Wc[(size_t)cls * KDIM + kpos]) : (u16)0;
    return;
  }
  blk -= 8192;
  if (blk < 256) {                        // W2f fragment layout
    int i = blk * 256 + tid;
    int i8 = i & 7;
    int l  = (i >> 3) & 63;
    int nt = (i >> 9) & 7;
    int wn = (i >> 12) & 1;
    int kh = (i >> 13) & 1;
    int kq = (i >> 14) & 3;
    int row = wn * 128 + nt * 16 + (l & 15);
    int k   = kq * 64 + kh * 32 + ((l >> 4) << 3) + i8;
    W2f[i] = f2h(W2[row * 256 + k]);
    return;
  }
  blk -= 256;
  if (blk < 128) {                        // W3f fragment layout
    int i = blk * 256 + tid;
    int i8 = i & 7;
    int l  = (i >> 3) & 63;
    int nt = (i >> 9) & 3;
    int wn = (i >> 11) & 1;
    int kh = (i >> 12) & 1;
    int kq = (i >> 13) & 3;
    int row = wn * 64 + nt * 16 + (l & 15);
    int k   = kq * 64 + kh * 32 + ((l >> 4) << 3) + i8;
    W3f[i] = f2h(W3[row * 256 + k]);
    return;
  }
  blk -= 128;
  if (blk < 4) {
    int m = blk * 256 + tid;
    int i = m >> 5, j = m & 31;
    const float* arow = adj + (size_t)m * N_NODES;
    int n[5]; float c[5];
    n[0] = m;                      c[0] = arow[m];
    n[1] = (i > 0)  ? m - 32 : m;  c[1] = (i > 0)  ? arow[m - 32] : 0.f;
    n[2] = (i < 31) ? m + 32 : m;  c[2] = (i < 31) ? arow[m + 32] : 0.f;
    n[3] = (j > 0)  ? m - 1  : m;  c[3] = (j > 0)  ? arow[m - 1]  : 0.f;
    n[4] = (j < 31) ? m + 1  : m;  c[4] = (j < 31) ? arow[m + 1]  : 0.f;
    float s = 0.f;
#pragma unroll
    for (int t = 0; t < 5; t++) { nbi[m * 5 + t] = n[t]; nbc[m * 5 + t] = c[t]; s += c[t]; }
    r[m] = s;
    return;
  }
  blk -= 4;
  if (blk == 0) {
    float4 v;
    v.x = W1[tid * 3]; v.y = W1[tid * 3 + 1]; v.z = W1[tid * 3 + 2]; v.w = b1[tid];
    ((float4*)w1p)[tid] = v;
    return;
  }
  blk -= 1;
  int idx = blk * 256 + tid;
  if (idx < 256 * NCLS) out[idx] = bc[idx % NCLS];
}

// ---------------- fused layer1+agg+layer2 (f16; B direct from L2) ----------------
// No Bs LDS, no global_load_lds at all: LDS 43 KB -> 3 blocks/CU (+50% waves).
// B fragments are per-lane coalesced 16 B L2 loads from W2f; barriers are now
// pure LDS fences (h1c / As visibility).
__global__ __launch_bounds__(256, 2) void l12mm_kernel(
    const float* __restrict__ x,     // [chunk,3,1024]
    const float* __restrict__ w1p,   // [256][4] f32: w0,w1,w2,b1
    const u16* __restrict__ W2f,     // B-fragment layout, 65536 f16
    const float* __restrict__ b2,    // [256]
    const float* __restrict__ r,     // [1024]
    const int* __restrict__ nbi, const float* __restrict__ nbc,
    u16* __restrict__ C)             // h2 [M,256] f16
{
  __shared__ u16 As[128 * 64];       // 16 KB (swizzled)
  __shared__ u16 h1c[192 * 64];      // 24 KB (swizzled)
  __shared__ float gxs[192][4];      // 3 KB  (gx0,gx1,gx2,rn) per halo node

  int m0 = blockIdx.x * 128;
  int b = m0 >> 10;
  int node0 = m0 & 1023;
  int e0 = node0 - 32;
  int tid = threadIdx.x;
  int w = tid >> 6, l = tid & 63;
  int wm = w >> 1, wn = w & 1;

  // prologue: halo gx
  if (tid < 192) {
    int n = e0 + tid;
    float4 gv = {0.f, 0.f, 0.f, 0.f};
    if (n >= 0 && n < N_NODES) {
      const float* xb = x + (size_t)b * 3072;
      float g0 = 0.f, g1 = 0.f, g2 = 0.f;
#pragma unroll
      for (int t = 0; t < 5; t++) {
        int nb = nbi[n * 5 + t]; float cv = nbc[n * 5 + t];
        g0 += cv * xb[nb];
        g1 += cv * xb[1024 + nb];
        g2 += cv * xb[2048 + nb];
      }
      gv.x = g0; gv.y = g1; gv.z = g2; gv.w = r[n];
    }
    *(float4*)&gxs[tid][0] = gv;
  }

  // phase-1 assignment: thread -> (8-ch octet cg, rows rb, rb+32, ..., rb+160)
  int cg = tid & 7;
  int rb = tid >> 3;                 // 0..31

#define L12_PHASE1(kq_) { \
    _Pragma("unroll") for (int jh = 0; jh < 2; jh++) { \
      float4 q_[4]; \
      _Pragma("unroll") for (int j = 0; j < 4; j++) \
        q_[j] = ((const float4*)w1p)[(kq_) * 64 + cg * 8 + jh * 4 + j]; \
      _Pragma("unroll") for (int i = 0; i < 6; i++) { \
        int row_ = rb + 32 * i; \
        float4 g_ = *(const float4*)&gxs[row_][0]; \
        float h_[4]; \
        _Pragma("unroll") for (int j = 0; j < 4; j++) \
          h_[j] = fmaxf(fmaf(g_.x, q_[j].x, fmaf(g_.y, q_[j].y, fmaf(g_.z, q_[j].z, g_.w * q_[j].w))), 0.f); \
        uint32_t pk_[2]; \
        pk_[0] = pkh(h_[0], h_[1]); pk_[1] = pkh(h_[2], h_[3]); \
        *(uint2*)&h1c[row_ * 64 + ((cg ^ (row_ & 7)) << 3) + jh * 4] = *(uint2*)pk_; \
      } \
    } }

  // phase-2 assignment: thread -> (out row arow, 32-ch half lo0)
  int arow = tid >> 1;
  int lo0 = (tid & 1) << 2;          // logical octet base 0/4
  int node = node0 + arow;
  int pidx[5]; _Float16 pch[5];
#pragma unroll
  for (int t = 0; t < 5; t++) {
    pidx[t] = nbi[node * 5 + t] - e0;    // always in [0,192)
    pch[t]  = (_Float16)nbc[node * 5 + t];
  }
  int asw = arow & 7;

#define L12_PHASE2() \
  _Pragma("unroll") for (int q = 0; q < 4; q++) { \
    int lo_ = lo0 + q; \
    h16x2 a0_ = {0, 0}, a1_ = {0, 0}, a2_ = {0, 0}, a3_ = {0, 0}; \
    _Pragma("unroll") for (int t = 0; t < 5; t++) { \
      int id_ = pidx[t]; \
      uint4 v_ = *(const uint4*)&h1c[id_ * 64 + ((lo_ ^ (id_ & 7)) << 3)]; \
      h16x2 c2_ = { pch[t], pch[t] }; \
      a0_ += c2_ * u2h2(v_.x); a1_ += c2_ * u2h2(v_.y); \
      a2_ += c2_ * u2h2(v_.z); a3_ += c2_ * u2h2(v_.w); \
    } \
    uint4 o_; \
    o_.x = h22u(a0_); o_.y = h22u(a1_); o_.z = h22u(a2_); o_.w = h22u(a3_); \
    *(uint4*)&As[arow * 64 + ((lo_ ^ asw) << 3)] = o_; \
  }

  __syncthreads();        // gxs ready
  L12_PHASE1(0);

  f32x4 acc[4][8] = {};
  int lrow = l & 15, lq = l >> 4;
  int s2 = lrow & 7;

  for (int kq = 0; kq < 4; kq++) {
    __syncthreads();            // (A) h1c(kq) visible; prev MFMA As reads done
    L12_PHASE2();               // h1c(kq) -> As
    __syncthreads();            // (B) As visible
    if (kq < 3) L12_PHASE1(kq + 1);   // co-scheduled with MFMA below

    const u16* pa = &As[(wm * 64 + lrow) * 64];
#pragma unroll
    for (int kh = 0; kh < 2; kh++) {
      int po = (((kh << 2) | lq) ^ s2) << 3;   // physical octet offset (As)
      const u16* wb = W2f + ((((size_t)kq * 2 + kh) * 2 + wn) << 12) + (l << 3);
      half8 af[4], bf[8];
#pragma unroll
      for (int t = 0; t < 4; t++)
        af[t] = *(const half8*)(pa + t * 16 * 64 + po);
#pragma unroll
      for (int t = 0; t < 8; t++)
        bf[t] = *(const half8*)(wb + ((size_t)t << 9));   // 16 B coalesced, L2
#pragma unroll
      for (int mt = 0; mt < 4; mt++)
#pragma unroll
        for (int nt = 0; nt < 8; nt++)
          acc[mt][nt] = __builtin_amdgcn_mfma_f32_16x16x32_f16(af[mt], bf[nt], acc[mt][nt], 0, 0, 0);
    }
  }
#undef L12_PHASE1
#undef L12_PHASE2

#pragma unroll
  for (int mt = 0; mt < 4; mt++)
#pragma unroll
    for (int nt = 0; nt < 8; nt++) {
      f32x4 v = acc[mt][nt];
      int col = wn * 128 + nt * 16 + lrow;
      float bs = b2[col];
#pragma unroll
      for (int i2 = 0; i2 < 4; i2++) {
        int row = m0 + wm * 64 + mt * 16 + lq * 4 + i2;
        float val = v[i2] + r[row & 1023] * bs;
        C[(size_t)row * 256 + col] = f2h(fmaxf(val, 0.f));
      }
    }
}

// ---------------- mm3agg (f16; B direct from L2; glds-staged h2 halo) ----------------
// LDS 40 KB -> 3 blocks/CU. Only remaining glds is the h2 halo stage.
__global__ __launch_bounds__(256, 2) void mm3agg_kernel(
    const u16* __restrict__ H,      // h2 [chunk*1024, 256] f16
    const u16* __restrict__ W3f,    // B-fragment layout, 32768 f16
    const float* __restrict__ bias, const float* __restrict__ r,
    const int* __restrict__ nbi, const float* __restrict__ nbc,
    const u16* __restrict__ Wcf,    // [KDIM/32][64][8] f16 B-frag layout
    float* __restrict__ out,        // [256,10] f32 (pre-initialized to bc)
    int b0)
{
  __shared__ u16 smem[20480];       // 40 KB: h2c (24K) | As (16K); h3s overlays
  u16* h2c = smem;                  // [192][64] swizzled
  u16* As  = smem + 12288;          // [128][64] swizzled
  __shared__ float cred[4][NCLS];

  int m0 = blockIdx.x * 128;
  int b = m0 >> 10;
  int node0 = m0 & 1023;
  int e0 = node0 - 32;
  int tid = threadIdx.x;
  int w = tid >> 6, l = tid & 63;
  int wm = w >> 1, wn = w & 1;

  const u16* hbase = H + ((size_t)b << 10) * 256;

  // h2c staging: 6 slots/thread; slot -> (row = slot>>3, po = slot&7).
  // LDS dst LINEAR (glds requirement); XOR swizzle on the GLOBAL source
  // column so h2c[row][po] holds logical octet po^(row&7). Clamped rows
  // are never consumed (nbi clamps + nbc=0 at boundaries).
#define M3_ISSUEH(kq) \
  _Pragma("unroll") for (int it = 0; it < 6; it++) { \
    int slot_ = it * 256 + tid; \
    int row_ = slot_ >> 3, po_ = slot_ & 7; \
    int grow_ = e0 + row_; \
    grow_ = grow_ < 0 ? 0 : (grow_ > 1023 ? 1023 : grow_); \
    async_copy16(hbase + (size_t)grow_ * 256 + ((po_ ^ (row_ & 7)) << 3) + (kq) * 64, \
                 &h2c[slot_ * 8]); \
  }

  // stencil assignment: thread -> (row arow, 32-ch half lo0)
  int arow = tid >> 1;
  int lo0 = (tid & 1) << 2;
  int node = node0 + arow;
  int pidx[5]; _Float16 pch[5];
#pragma unroll
  for (int t = 0; t < 5; t++) {
    pidx[t] = nbi[node * 5 + t] - e0;    // always in [0,192)
    pch[t]  = (_Float16)nbc[node * 5 + t];
  }
  int asw = arow & 7;

#define M3_PHASE2() \
  _Pragma("unroll") for (int q = 0; q < 4; q++) { \
    int lo_ = lo0 + q; \
    h16x2 a0_ = {0, 0}, a1_ = {0, 0}, a2_ = {0, 0}, a3_ = {0, 0}; \
    _Pragma("unroll") for (int t = 0; t < 5; t++) { \
      int id_ = pidx[t]; \
      uint4 v_ = *(const uint4*)&h2c[id_ * 64 + ((lo_ ^ (id_ & 7)) << 3)]; \
      h16x2 c2_ = { pch[t], pch[t] }; \
      a0_ += c2_ * u2h2(v_.x); a1_ += c2_ * u2h2(v_.y); \
      a2_ += c2_ * u2h2(v_.z); a3_ += c2_ * u2h2(v_.w); \
    } \
    uint4 o_; \
    o_.x = h22u(a0_); o_.y = h22u(a1_); o_.z = h22u(a2_); o_.w = h22u(a3_); \
    *(uint4*)&As[arow * 64 + ((lo_ ^ asw) << 3)] = o_; \
  }

  M3_ISSUEH(0);

  f32x4 acc[4][4] = {};
  int lrow = l & 15, lq = l >> 4;
  int s = lrow & 7;

#pragma unroll
  for (int kq = 0; kq < 4; kq++) {
    __syncthreads();            // (A) h2c(kq) drained+visible; prev As reads done
    M3_PHASE2();                // h2c(kq) -> As (stencil agg)
    __syncthreads();            // (B) As visible; all h2c(kq) reads done
    if (kq < 3) M3_ISSUEH(kq + 1);   // h2c(kq+1) in flight during MFMA

    const u16* pa = &As[(wm * 64 + lrow) * 64];
#pragma unroll
    for (int kh = 0; kh < 2; kh++) {
      int po = (((kh << 2) | lq) ^ s) << 3;   // physical octet offset (As)
      const u16* wb = W3f + ((((size_t)kq * 2 + kh) * 2 + wn) << 11) + (l << 3);
      half8 af[4], bf[4];
#pragma unroll
      for (int t = 0; t < 4; t++) {
        af[t] = *(const half8*)(pa + t * 16 * 64 + po);
        bf[t] = *(const half8*)(wb + ((size_t)t << 9));   // 16 B coalesced, L2
      }
#pragma unroll
      for (int mt = 0; mt < 4; mt++)
#pragma unroll
        for (int nt = 0; nt < 4; nt++)
          acc[mt][nt] = __builtin_amdgcn_mfma_f32_16x16x32_f16(af[mt], bf[nt], acc[mt][nt], 0, 0, 0);
    }
  }
#undef M3_ISSUEH
#undef M3_PHASE2

  // ---- epilogue: h3 -> LDS tile (overlays h2c+As), classifier via MFMA ----
  __syncthreads();                 // K-loop reads done
  u16* h3s = smem;                 // [128][128] f16 = 32 KB (fits in 40 KB)
#pragma unroll
  for (int mt = 0; mt < 4; mt++)
#pragma unroll
    for (int nt = 0; nt < 4; nt++) {
      f32x4 v = acc[mt][nt];
      int col = wn * 64 + nt * 16 + lrow;
      float bs = bias[col];
#pragma unroll
      for (int i2 = 0; i2 < 4; i2++) {
        int lr = wm * 64 + mt * 16 + lq * 4 + i2;
        float h = fmaxf(v[i2] + r[(m0 + lr) & 1023] * bs, 0.f);
        h3s[lr * 128 + col] = f2h(h);
      }
    }
  __syncthreads();                 // h3 tile visible

  // wave w covers local kb in [w*128, w*128+128); global kb = node0*4 + kb
  const u16* wp = Wcf + ((size_t)(node0 * 4 + w * 128) * 64 + l) * 8;
  const u16* ap = h3s + w * 128 * 32 + lq * 8;
  f32x4 cacc = {};
#pragma unroll 8
  for (int t = 0; t < 128; t++) {
    half8 bfv = *(const half8*)(wp + (size_t)t * 512);  // 16 B coalesced, L2
    half8 afv = *(const half8*)(ap + t * 32);           // LDS broadcast
    cacc = __builtin_amdgcn_mfma_f32_16x16x32_f16(afv, bfv, cacc, 0, 0, 0);
  }
  if (l < NCLS) cred[w][l] = cacc[0];   // col = l = class; full k-sum per lane
  __syncthreads();
  if (tid < NCLS) {
    int bimg = b0 + (m0 >> 10);
    atomicAdd(&out[bimg * NCLS + tid],
              cred[0][tid] + cred[1][tid] + cred[2][tid] + cred[3][tid]);
  }
}

extern "C" void kernel_launch(void* const* d_in, const int* in_sizes, int n_in,
                              void* d_out, int out_size, void* d_ws, size_t ws_size,
                              hipStream_t stream) {
  const float* x   = (const float*)d_in[0];
  const float* W1  = (const float*)d_in[1];
  const float* b1  = (const float*)d_in[2];
  const float* W2  = (const float*)d_in[3];
  const float* b2  = (const float*)d_in[4];
  const float* W3  = (const float*)d_in[5];
  const float* b3  = (const float*)d_in[6];
  const float* Wc  = (const float*)d_in[7];
  const float* bc  = (const float*)d_in[8];
  const float* adj = (const float*)d_in[9];
  float* out = (float*)d_out;
  const int B = 256;

  uint8_t* ws = (uint8_t*)d_ws;
  u16* W2f = (u16*)ws;  ws += (size_t)256 * 256 * 2;
  u16* W3f = (u16*)ws;  ws += (size_t)128 * 256 * 2;
  u16* Wcf = (u16*)ws;  ws += (size_t)KDIM * 16 * 2;
  float* rr  = (float*)ws; ws += 1024 * 4;
  int*   nbi = (int*)ws;   ws += 1024 * 5 * 4;
  float* nbc = (float*)ws; ws += 1024 * 5 * 4;
  float* w1p = (float*)ws; ws += 256 * 4 * 4;
  uintptr_t al = ((uintptr_t)ws + 255) & ~(uintptr_t)255;
  ws = (uint8_t*)al;
  size_t used = (size_t)(ws - (uint8_t*)d_ws);
  size_t avail = (ws_size > used) ? ws_size - used : 0;
  int chunk = 256;
  while (chunk > 32 && (size_t)chunk * 1024 * 256 * 2 > avail) chunk >>= 1;
  u16* bufA = (u16*)ws;   // h2 only; h3 is never materialized

  prep_all_kernel<<<PREP_GRID, 256, 0, stream>>>(W2, W3, Wc, W1, b1, bc, adj,
                                                 W2f, W3f, Wcf, w1p, nbi, nbc, rr, out);

  for (int b0 = 0; b0 < B; b0 += chunk) {
    const float* xb = x + (size_t)b0 * 3 * 1024;
    int M = chunk * 1024;
    // h2 = relu((A.h1) W2^T + r.b2) fused from x -> bufA
    l12mm_kernel<<<M / 128, 256, 0, stream>>>(xb, w1p, W2f, b2, rr, nbi, nbc, bufA);
    // h3 = relu((A.h2) W3^T + r.b3) in-LDS, classifier via MFMA
    mm3agg_kernel<<<M / 128, 256, 0, stream>>>(bufA, W3f, b3, rr, nbi, nbc, Wcf, out, b0);
  }
}

// Round 14
// 223.508 us; speedup vs baseline: 1.1057x; 1.1057x over previous
//
#include <hip/hip_runtime.h>
#include <stdint.h>

#define N_NODES 1024
#define NCLS 10
#define KDIM 131072  // 1024*128

typedef unsigned short u16;
typedef _Float16 half8 __attribute__((ext_vector_type(8)));
typedef _Float16 h16x2 __attribute__((ext_vector_type(2)));
typedef __fp16 fp16x2 __attribute__((ext_vector_type(2)));
typedef float f32x4 __attribute__((ext_vector_type(4)));

__device__ __forceinline__ u16 f2h(float f) {
  union { _Float16 h; u16 u; } v; v.h = (_Float16)f; return v.u;
}
__device__ __forceinline__ uint32_t pkh(float a, float b) {
#if __has_builtin(__builtin_amdgcn_cvt_pkrtz)
  fp16x2 r = __builtin_amdgcn_cvt_pkrtz(a, b);
  union { fp16x2 v; uint32_t u; } c; c.v = r; return c.u;
#else
  union { _Float16 h[2]; uint32_t u; } c;
  c.h[0] = (_Float16)a; c.h[1] = (_Float16)b; return c.u;
#endif
}
__device__ __forceinline__ h16x2 u2h2(uint32_t u) {
  union { uint32_t u; h16x2 v; } c; c.u = u; return c.v;
}
__device__ __forceinline__ uint32_t h22u(h16x2 v) {
  union { h16x2 v; uint32_t u; } c; c.v = v; return c.u;
}
__device__ __forceinline__ h16x2 h2max0(h16x2 a) {
#if __has_builtin(__builtin_elementwise_max)
  h16x2 z = {0, 0};
  return __builtin_elementwise_max(a, z);
#else
  h16x2 r;
  r.x = a.x > (_Float16)0 ? a.x : (_Float16)0;
  r.y = a.y > (_Float16)0 ? a.y : (_Float16)0;
  return r;
#endif
}

__device__ __forceinline__ void async_copy16(const u16* g, u16* l) {
  __builtin_amdgcn_global_load_lds(
      (const __attribute__((address_space(1))) void*)g,
      (__attribute__((address_space(3))) void*)l, 16, 0, 0);
}

// ---------------- single merged prep kernel (R12 form + w1h pair table) ----------------
// blockIdx ranges:
//   [0, 8192)        : Wcf  (classifier weights in MFMA B-fragment layout)
//   [8192, 8448)     : W2b  (256x256 f32->f16, plain row-major)
//   [8448, 8576)     : W3b  (128x256 f32->f16, plain row-major)
//   [8576, 8580)     : adj -> stencil tables (nbi, nbc, r)
//   [8580]           : w1h  (W1|b1 packed f16 channel-pairs: [pair 0..127][comp 0..3],
//                      entry = u32{v(2p,c), v(2p+1,c)}, v(ch,c)= c<3 ? W1[ch*3+c] : b1[ch])
//   [8581, 8591)     : out init (bc broadcast)
#define PREP_GRID 8591
__global__ __launch_bounds__(256) void prep_all_kernel(
    const float* __restrict__ W2, const float* __restrict__ W3,
    const float* __restrict__ Wc, const float* __restrict__ W1,
    const float* __restrict__ b1, const float* __restrict__ bc,
    const float* __restrict__ adj,
    u16* __restrict__ W2b, u16* __restrict__ W3b, u16* __restrict__ Wcf,
    uint32_t* __restrict__ w1h, int* __restrict__ nbi, float* __restrict__ nbc,
    float* __restrict__ r, float* __restrict__ out)
{
  int blk = blockIdx.x;
  int tid = threadIdx.x;
  if (blk < 8192) {                       // Wcf: i over KDIM*16, coalesced store
    int i = blk * 256 + tid;
    int kb  = i >> 9;
    int l   = (i >> 3) & 63;
    int i8  = i & 7;
    int cls = l & 15;
    int kpos = kb * 32 + ((l >> 4) << 3) + i8;
    Wcf[i] = (cls < NCLS) ? f2h(Wc[(size_t)cls * KDIM + kpos]) : (u16)0;
    return;
  }
  blk -= 8192;
  if (blk < 256) { int i = blk * 256 + tid; W2b[i] = f2h(W2[i]); return; }
  blk -= 256;
  if (blk < 128) { int i = blk * 256 + tid; W3b[i] = f2h(W3[i]); return; }
  blk -= 128;
  if (blk < 4) {
    int m = blk * 256 + tid;
    int i = m >> 5, j = m & 31;
    const float* arow = adj + (size_t)m * N_NODES;
    int n[5]; float c[5];
    n[0] = m;                      c[0] = arow[m];
    n[1] = (i > 0)  ? m - 32 : m;  c[1] = (i > 0)  ? arow[m - 32] : 0.f;
    n[2] = (i < 31) ? m + 32 : m;  c[2] = (i < 31) ? arow[m + 32] : 0.f;
    n[3] = (j > 0)  ? m - 1  : m;  c[3] = (j > 0)  ? arow[m - 1]  : 0.f;
    n[4] = (j < 31) ? m + 1  : m;  c[4] = (j < 31) ? arow[m + 1]  : 0.f;
    float s = 0.f;
#pragma unroll
    for (int t = 0; t < 5; t++) { nbi[m * 5 + t] = n[t]; nbc[m * 5 + t] = c[t]; s += c[t]; }
    r[m] = s;
    return;
  }
  blk -= 4;
  if (blk == 0) {
#pragma unroll
    for (int e0i = 0; e0i < 2; e0i++) {
      int e = e0i * 256 + tid;          // [0,512)
      int p = e >> 2, c = e & 3;
      int ch0 = 2 * p, ch1 = 2 * p + 1;
      float v0 = (c < 3) ? W1[ch0 * 3 + c] : b1[ch0];
      float v1 = (c < 3) ? W1[ch1 * 3 + c] : b1[ch1];
      w1h[e] = pkh(v0, v1);
    }
    return;
  }
  blk -= 1;
  int idx = blk * 256 + tid;
  if (idx < 256 * NCLS) out[idx] = bc[idx % NCLS];
}

// ---------------- fused layer1+agg+layer2 (R12 schedule; phase1 packed f16) ----------------
// Phase1 now channel-pairwise in v_pk_fma_f16 / v_pk_max_f16: ~20 packed ops
// per row-octet vs 44 scalar, result born packed (no pkh repack). Named h16x2
// scalars only (R9 SROA spill lesson).
__global__ __launch_bounds__(256, 2) void l12mm_kernel(
    const float* __restrict__ x,     // [chunk,3,1024]
    const uint32_t* __restrict__ w1h,// [128 pairs][4 comps] packed f16 pairs
    const u16* __restrict__ W2b,     // [256,256] f16
    const float* __restrict__ b2,    // [256]
    const float* __restrict__ r,     // [1024]
    const int* __restrict__ nbi, const float* __restrict__ nbc,
    u16* __restrict__ C)             // h2 [M,256] f16
{
  const int K = 256;
  __shared__ u16 As[128 * 64];       // 16 KB (swizzled)
  __shared__ u16 Bs[256 * 64];       // 32 KB (glds source-swizzled)
  __shared__ u16 h1c[192 * 64];      // 24 KB (swizzled)
  __shared__ uint32_t gxs2[192][4];  // 3 KB  broadcast f16 pairs {g0,g0}{g1,g1}{g2,g2}{rn,rn}

  int m0 = blockIdx.x * 128;
  int b = m0 >> 10;
  int node0 = m0 & 1023;
  int e0 = node0 - 32;
  int tid = threadIdx.x;
  int w = tid >> 6, l = tid & 63;
  int wm = w >> 1, wn = w & 1;

  // B staging (proven swizzled-glds layout)
  int r8 = l >> 3, oct = l & 7;
  int so = (oct ^ r8) << 3;
  const u16* gb0 = W2b + (size_t)(w * 64 + r8) * K + so;

#define L12_ISSUEB(kq) \
  _Pragma("unroll") for (int q = 0; q < 8; q++) \
    async_copy16(gb0 + (size_t)q * 8 * K + (kq) * 64, &Bs[(w * 64 + q * 8) * 64]);

  L12_ISSUEB(0);

  // prologue: halo gx (f32 accumulate, stored as broadcast f16 pairs)
  if (tid < 192) {
    int n = e0 + tid;
    float g0 = 0.f, g1 = 0.f, g2 = 0.f, rn = 0.f;
    if (n >= 0 && n < N_NODES) {
      const float* xb = x + (size_t)b * 3072;
#pragma unroll
      for (int t = 0; t < 5; t++) {
        int nb = nbi[n * 5 + t]; float cv = nbc[n * 5 + t];
        g0 += cv * xb[nb];
        g1 += cv * xb[1024 + nb];
        g2 += cv * xb[2048 + nb];
      }
      rn = r[n];
    }
    uint4 gv;
    gv.x = pkh(g0, g0); gv.y = pkh(g1, g1);
    gv.z = pkh(g2, g2); gv.w = pkh(rn, rn);
    *(uint4*)&gxs2[tid][0] = gv;
  }

  // phase-1 assignment: thread -> (8-ch octet cg, rows rb, rb+32, ..., rb+160)
  int cg = tid & 7;
  int rb = tid >> 3;                 // 0..31

#define L12_PHASE1(kq_) { \
    uint4 wp0_ = ((const uint4*)w1h)[(kq_) * 32 + cg * 4 + 0]; \
    uint4 wp1_ = ((const uint4*)w1h)[(kq_) * 32 + cg * 4 + 1]; \
    uint4 wp2_ = ((const uint4*)w1h)[(kq_) * 32 + cg * 4 + 2]; \
    uint4 wp3_ = ((const uint4*)w1h)[(kq_) * 32 + cg * 4 + 3]; \
    _Pragma("unroll") for (int i = 0; i < 6; i++) { \
      int row_ = rb + 32 * i; \
      uint4 g_ = *(const uint4*)&gxs2[row_][0]; \
      h16x2 gx_ = u2h2(g_.x), gy_ = u2h2(g_.y), gz_ = u2h2(g_.z), gw_ = u2h2(g_.w); \
      h16x2 h0_ = h2max0(gx_ * u2h2(wp0_.x) + gy_ * u2h2(wp0_.y) + gz_ * u2h2(wp0_.z) + gw_ * u2h2(wp0_.w)); \
      h16x2 h1_ = h2max0(gx_ * u2h2(wp1_.x) + gy_ * u2h2(wp1_.y) + gz_ * u2h2(wp1_.z) + gw_ * u2h2(wp1_.w)); \
      h16x2 h2_ = h2max0(gx_ * u2h2(wp2_.x) + gy_ * u2h2(wp2_.y) + gz_ * u2h2(wp2_.z) + gw_ * u2h2(wp2_.w)); \
      h16x2 h3_ = h2max0(gx_ * u2h2(wp3_.x) + gy_ * u2h2(wp3_.y) + gz_ * u2h2(wp3_.z) + gw_ * u2h2(wp3_.w)); \
      uint4 o_; \
      o_.x = h22u(h0_); o_.y = h22u(h1_); o_.z = h22u(h2_); o_.w = h22u(h3_); \
      *(uint4*)&h1c[row_ * 64 + ((cg ^ (row_ & 7)) << 3)] = o_; \
    } }

  // phase-2 assignment: thread -> (out row arow, 32-ch half lo0)
  int arow = tid >> 1;
  int lo0 = (tid & 1) << 2;          // logical octet base 0/4
  int node = node0 + arow;
  int pidx[5]; _Float16 pch[5];
#pragma unroll
  for (int t = 0; t < 5; t++) {
    pidx[t] = nbi[node * 5 + t] - e0;    // always in [0,192)
    pch[t]  = (_Float16)nbc[node * 5 + t];
  }
  int asw = arow & 7;

#define L12_PHASE2() \
  _Pragma("unroll") for (int q = 0; q < 4; q++) { \
    int lo_ = lo0 + q; \
    h16x2 a0_ = {0, 0}, a1_ = {0, 0}, a2_ = {0, 0}, a3_ = {0, 0}; \
    _Pragma("unroll") for (int t = 0; t < 5; t++) { \
      int id_ = pidx[t]; \
      uint4 v_ = *(const uint4*)&h1c[id_ * 64 + ((lo_ ^ (id_ & 7)) << 3)]; \
      h16x2 c2_ = { pch[t], pch[t] }; \
      a0_ += c2_ * u2h2(v_.x); a1_ += c2_ * u2h2(v_.y); \
      a2_ += c2_ * u2h2(v_.z); a3_ += c2_ * u2h2(v_.w); \
    } \
    uint4 o_; \
    o_.x = h22u(a0_); o_.y = h22u(a1_); o_.z = h22u(a2_); o_.w = h22u(a3_); \
    *(uint4*)&As[arow * 64 + ((lo_ ^ asw) << 3)] = o_; \
  }

  __syncthreads();        // gxs2 ready
  L12_PHASE1(0);

  f32x4 acc[4][8] = {};
  int lrow = l & 15, lq = l >> 4;
  int s2 = lrow & 7;

  for (int kq = 0; kq < 4; kq++) {
    __syncthreads();            // (A) h1c(kq) visible; prev MFMA done (As/Bs free)
    if (kq) L12_ISSUEB(kq);     // W2 chunk kq in flight under phase2
    L12_PHASE2();               // h1c(kq) -> As
    __syncthreads();            // (B) As ready; Bs(kq) glds drained
    if (kq < 3) L12_PHASE1(kq + 1);   // co-scheduled with MFMA below

    const u16* pa = &As[(wm * 64 + lrow) * 64];
    const u16* pb = &Bs[(wn * 128 + lrow) * 64];
#pragma unroll
    for (int kh = 0; kh < 2; kh++) {
      int po = (((kh << 2) | lq) ^ s2) << 3;   // physical octet offset (A and B)
      half8 af[4], bf[8];
#pragma unroll
      for (int t = 0; t < 4; t++)
        af[t] = *(const half8*)(pa + t * 16 * 64 + po);
#pragma unroll
      for (int t = 0; t < 8; t++)
        bf[t] = *(const half8*)(pb + t * 16 * 64 + po);
#pragma unroll
      for (int mt = 0; mt < 4; mt++)
#pragma unroll
        for (int nt = 0; nt < 8; nt++)
          acc[mt][nt] = __builtin_amdgcn_mfma_f32_16x16x32_f16(af[mt], bf[nt], acc[mt][nt], 0, 0, 0);
    }
  }
#undef L12_ISSUEB
#undef L12_PHASE1
#undef L12_PHASE2

#pragma unroll
  for (int mt = 0; mt < 4; mt++)
#pragma unroll
    for (int nt = 0; nt < 8; nt++) {
      f32x4 v = acc[mt][nt];
      int col = wn * 128 + nt * 16 + lrow;
      float bs = b2[col];
#pragma unroll
      for (int i2 = 0; i2 < 4; i2++) {
        int row = m0 + wm * 64 + mt * 16 + lq * 4 + i2;
        float val = v[i2] + r[row & 1023] * bs;
        C[(size_t)row * 256 + col] = f2h(fmaxf(val, 0.f));
      }
    }
}

// ---------------- mm3agg v2 (EXACT R12 form) ----------------
// glds-staged h2 halo (source-swizzled) + pk_fma_f16 stencil + f16 MFMA +
// MFMA classifier. h3 never touches HBM.
__global__ __launch_bounds__(256, 2) void mm3agg_kernel(
    const u16* __restrict__ H,      // h2 [chunk*1024, 256] f16
    const u16* __restrict__ W,      // W3b [128, 256] f16
    const float* __restrict__ bias, const float* __restrict__ r,
    const int* __restrict__ nbi, const float* __restrict__ nbc,
    const u16* __restrict__ Wcf,    // [KDIM/32][64][8] f16 B-frag layout
    float* __restrict__ out,        // [256,10] f32 (pre-initialized to bc)
    int b0)
{
  const int K = 256;
  __shared__ u16 smem[28672];       // 56 KB: h2c | As | Bs (h3s overlays after K-loop)
  u16* h2c = smem;                  // [192][64] swizzled, 24 KB
  u16* As  = smem + 12288;          // [128][64] swizzled, 16 KB
  u16* Bs  = smem + 20480;          // [128][64] source-swizzled, 16 KB
  __shared__ float cred[4][NCLS];

  int m0 = blockIdx.x * 128;
  int b = m0 >> 10;
  int node0 = m0 & 1023;
  int e0 = node0 - 32;
  int tid = threadIdx.x;
  int w = tid >> 6, l = tid & 63;
  int wm = w >> 1, wn = w & 1;

  const u16* hbase = H + ((size_t)b << 10) * 256;

  // B staging (source-swizzled glds, proven layout)
  int r8 = l >> 3, oct = l & 7;
  int so = (oct ^ r8) << 3;
  const u16* gb0 = W + (size_t)(w * 32 + r8) * K + so;

#define M3_ISSUEB(kq) \
  _Pragma("unroll") for (int q = 0; q < 4; q++) \
    async_copy16(gb0 + (size_t)q * 8 * K + (kq) * 64, &Bs[(w * 32 + q * 8) * 64]);

  // h2c staging: 6 slots/thread; slot -> (row = slot>>3, po = slot&7).
  // LDS dst LINEAR (glds requirement); XOR swizzle on the GLOBAL source
  // column so h2c[row][po] holds logical octet po^(row&7). Clamped rows
  // are never consumed (nbi clamps + nbc=0 at boundaries).
#define M3_ISSUEH(kq) \
  _Pragma("unroll") for (int it = 0; it < 6; it++) { \
    int slot_ = it * 256 + tid; \
    int row_ = slot_ >> 3, po_ = slot_ & 7; \
    int grow_ = e0 + row_; \
    grow_ = grow_ < 0 ? 0 : (grow_ > 1023 ? 1023 : grow_); \
    async_copy16(hbase + (size_t)grow_ * 256 + ((po_ ^ (row_ & 7)) << 3) + (kq) * 64, \
                 &h2c[slot_ * 8]); \
  }

  // stencil assignment: thread -> (row arow, 32-ch half lo0)
  int arow = tid >> 1;
  int lo0 = (tid & 1) << 2;
  int node = node0 + arow;
  int pidx[5]; _Float16 pch[5];
#pragma unroll
  for (int t = 0; t < 5; t++) {
    pidx[t] = nbi[node * 5 + t] - e0;    // always in [0,192)
    pch[t]  = (_Float16)nbc[node * 5 + t];
  }
  int asw = arow & 7;

#define M3_PHASE2() \
  _Pragma("unroll") for (int q = 0; q < 4; q++) { \
    int lo_ = lo0 + q; \
    h16x2 a0_ = {0, 0}, a1_ = {0, 0}, a2_ = {0, 0}, a3_ = {0, 0}; \
    _Pragma("unroll") for (int t = 0; t < 5; t++) { \
      int id_ = pidx[t]; \
      uint4 v_ = *(const uint4*)&h2c[id_ * 64 + ((lo_ ^ (id_ & 7)) << 3)]; \
      h16x2 c2_ = { pch[t], pch[t] }; \
      a0_ += c2_ * u2h2(v_.x); a1_ += c2_ * u2h2(v_.y); \
      a2_ += c2_ * u2h2(v_.z); a3_ += c2_ * u2h2(v_.w); \
    } \
    uint4 o_; \
    o_.x = h22u(a0_); o_.y = h22u(a1_); o_.z = h22u(a2_); o_.w = h22u(a3_); \
    *(uint4*)&As[arow * 64 + ((lo_ ^ asw) << 3)] = o_; \
  }

  M3_ISSUEB(0);
  M3_ISSUEH(0);

  f32x4 acc[4][4] = {};
  int lrow = l & 15, lq = l >> 4;
  int s = lrow & 7;

#pragma unroll
  for (int kq = 0; kq < 4; kq++) {
    __syncthreads();            // (A) h2c(kq) drained+visible; prev As/Bs reads done
    if (kq) M3_ISSUEB(kq);      // Bs(kq) in flight under phase2, drained at (B)
    M3_PHASE2();                // h2c(kq) -> As (stencil agg)
    __syncthreads();            // (B) As visible; Bs(kq) drained
    if (kq < 3) M3_ISSUEH(kq + 1);   // h2c(kq+1) in flight during MFMA

    const u16* pa = &As[(wm * 64 + lrow) * 64];
    const u16* pb = &Bs[(wn * 64 + lrow) * 64];
#pragma unroll
    for (int kh = 0; kh < 2; kh++) {
      int po = (((kh << 2) | lq) ^ s) << 3;   // physical octet offset (A and B)
      half8 af[4], bf[4];
#pragma unroll
      for (int t = 0; t < 4; t++) {
        af[t] = *(const half8*)(pa + t * 16 * 64 + po);
        bf[t] = *(const half8*)(pb + t * 16 * 64 + po);
      }
#pragma unroll
      for (int mt = 0; mt < 4; mt++)
#pragma unroll
        for (int nt = 0; nt < 4; nt++)
          acc[mt][nt] = __builtin_amdgcn_mfma_f32_16x16x32_f16(af[mt], bf[nt], acc[mt][nt], 0, 0, 0);
    }
  }
#undef M3_ISSUEB
#undef M3_ISSUEH
#undef M3_PHASE2

  // ---- epilogue: h3 -> LDS tile (overlays h2c+As), classifier via MFMA ----
  __syncthreads();                 // K-loop reads of As/Bs done
  u16* h3s = smem;                 // [128][128] f16 = 32 KB
#pragma unroll
  for (int mt = 0; mt < 4; mt++)
#pragma unroll
    for (int nt = 0; nt < 4; nt++) {
      f32x4 v = acc[mt][nt];
      int col = wn * 64 + nt * 16 + lrow;
      float bs = bias[col];
#pragma unroll
      for (int i2 = 0; i2 < 4; i2++) {
        int lr = wm * 64 + mt * 16 + lq * 4 + i2;
        float h = fmaxf(v[i2] + r[(m0 + lr) & 1023] * bs, 0.f);
        h3s[lr * 128 + col] = f2h(h);
      }
    }
  __syncthreads();                 // h3 tile visible

  // wave w covers local kb in [w*128, w*128+128); global kb = node0*4 + kb
  const u16* wp = Wcf + ((size_t)(node0 * 4 + w * 128) * 64 + l) * 8;
  const u16* ap = h3s + w * 128 * 32 + lq * 8;
  f32x4 cacc = {};
#pragma unroll 8
  for (int t = 0; t < 128; t++) {
    half8 bfv = *(const half8*)(wp + (size_t)t * 512);  // 16 B coalesced, L2
    half8 afv = *(const half8*)(ap + t * 32);           // LDS broadcast
    cacc = __builtin_amdgcn_mfma_f32_16x16x32_f16(afv, bfv, cacc, 0, 0, 0);
  }
  if (l < NCLS) cred[w][l] = cacc[0];   // col = l = class; full k-sum per lane
  __syncthreads();
  if (tid < NCLS) {
    int bimg = b0 + (m0 >> 10);
    atomicAdd(&out[bimg * NCLS + tid],
              cred[0][tid] + cred[1][tid] + cred[2][tid] + cred[3][tid]);
  }
}

extern "C" void kernel_launch(void* const* d_in, const int* in_sizes, int n_in,
                              void* d_out, int out_size, void* d_ws, size_t ws_size,
                              hipStream_t stream) {
  const float* x   = (const float*)d_in[0];
  const float* W1  = (const float*)d_in[1];
  const float* b1  = (const float*)d_in[2];
  const float* W2  = (const float*)d_in[3];
  const float* b2  = (const float*)d_in[4];
  const float* W3  = (const float*)d_in[5];
  const float* b3  = (const float*)d_in[6];
  const float* Wc  = (const float*)d_in[7];
  const float* bc  = (const float*)d_in[8];
  const float* adj = (const float*)d_in[9];
  float* out = (float*)d_out;
  const int B = 256;

  uint8_t* ws = (uint8_t*)d_ws;
  u16* W2b = (u16*)ws;  ws += (size_t)256 * 256 * 2;
  u16* W3b = (u16*)ws;  ws += (size_t)128 * 256 * 2;
  u16* Wcf = (u16*)ws;  ws += (size_t)KDIM * 16 * 2;
  float* rr  = (float*)ws; ws += 1024 * 4;
  int*   nbi = (int*)ws;   ws += 1024 * 5 * 4;
  float* nbc = (float*)ws; ws += 1024 * 5 * 4;
  uint32_t* w1h = (uint32_t*)ws; ws += 512 * 4;
  uintptr_t al = ((uintptr_t)ws + 255) & ~(uintptr_t)255;
  ws = (uint8_t*)al;
  size_t used = (size_t)(ws - (uint8_t*)d_ws);
  size_t avail = (ws_size > used) ? ws_size - used : 0;
  int chunk = 256;
  while (chunk > 32 && (size_t)chunk * 1024 * 256 * 2 > avail) chunk >>= 1;
  u16* bufA = (u16*)ws;   // h2 only; h3 is never materialized

  prep_all_kernel<<<PREP_GRID, 256, 0, stream>>>(W2, W3, Wc, W1, b1, bc, adj,
                                                 W2b, W3b, Wcf, w1h, nbi, nbc, rr, out);

  for (int b0 = 0; b0 < B; b0 += chunk) {
    const float* xb = x + (size_t)b0 * 3 * 1024;
    int M = chunk * 1024;
    // h2 = relu((A.h1) W2^T + r.b2) fused from x -> bufA
    l12mm_kernel<<<M / 128, 256, 0, stream>>>(xb, w1h, W2b, b2, rr, nbi, nbc, bufA);
    // h3 = relu((A.h2) W3^T + r.b3) in-LDS, classifier via MFMA
    mm3agg_kernel<<<M / 128, 256, 0, stream>>>(bufA, W3b, b3, rr, nbi, nbc, Wcf, out, b0);
  }
}